// Round 1
// baseline (980.741 us; speedup 1.0000x reference)
//
#include <hip/hip_runtime.h>
#include <math.h>

#define NN 8192
#define DD 256
#define FF 64
#define LEAKY 0.2f

__device__ __forceinline__ float lrelu(float x) { return x > 0.f ? x : LEAKY * x; }

// Kernel 1: h = features @ W  (8192x256 @ 256x64), plus s1 = h@a1, s2 = h@a2.
// One block = 16 rows, 256 threads (4 waves x 4 rows each, lane = output col f).
__global__ __launch_bounds__(256) void k_h(
    const float* __restrict__ feat, const float* __restrict__ W,
    const float* __restrict__ a, float* __restrict__ h,
    float* __restrict__ s1, float* __restrict__ s2) {
  __shared__ float fsh[16][DD];
  const int t = threadIdx.x;
  const int i0 = blockIdx.x * 16;
  // stage 16 feature rows (16KB) coalesced as float4
  const float4* fsrc = (const float4*)(feat + (size_t)i0 * DD);
  float4* fdst = (float4*)(&fsh[0][0]);
#pragma unroll
  for (int k = 0; k < 4; ++k) fdst[t + 256 * k] = fsrc[t + 256 * k];
  __syncthreads();
  const int lane = t & 63;
  const int w = t >> 6;
  float acc[4] = {0.f, 0.f, 0.f, 0.f};
  for (int d = 0; d < DD; ++d) {
    float wv = W[d * FF + lane];  // coalesced across lanes, L2-resident
#pragma unroll
    for (int r = 0; r < 4; ++r) acc[r] = fmaf(fsh[w * 4 + r][d], wv, acc[r]);
  }
  const float a1v = a[lane], a2v = a[FF + lane];
#pragma unroll
  for (int r = 0; r < 4; ++r) {
    int i = i0 + w * 4 + r;
    h[(size_t)i * FF + lane] = acc[r];
    float v1 = acc[r] * a1v, v2 = acc[r] * a2v;
#pragma unroll
    for (int m = 32; m > 0; m >>= 1) {
      v1 += __shfl_xor(v1, m);
      v2 += __shfl_xor(v2, m);
    }
    if (lane == 0) { s1[i] = v1; s2[i] = v2; }
  }
}

// Kernel 1b: s2max = max(s2)
__global__ __launch_bounds__(256) void k_s2max(const float* __restrict__ s2,
                                               float* __restrict__ s2max) {
  __shared__ float red[256];
  float m = -1e30f;
  for (int j = threadIdx.x; j < NN; j += 256) m = fmaxf(m, s2[j]);
  red[threadIdx.x] = m;
  __syncthreads();
  for (int s = 128; s > 0; s >>= 1) {
    if (threadIdx.x < s) red[threadIdx.x] = fmaxf(red[threadIdx.x], red[threadIdx.x + s]);
    __syncthreads();
  }
  if (threadIdx.x == 0) *s2max = red[0];
}

// Kernel 2: fused mask + softmax + attention@h + elu.
// Block = 16 rows (i), 256 threads = 4 waves x 4 rows. j tiled by 256.
// Phase A (lane = j/4): p = adj ? exp(lrelu(s1+s2) - m_i) : 0 -> p_lds (wave-private rows)
// Phase B (lane = d):   acc[r] += p_lds[row][jj] * h[j][d]   (broadcast LDS reads)
// Each wave only touches its own 4 rows of p_lds -> NO barriers in the loop.
__global__ __launch_bounds__(256) void k_attn(
    const int* __restrict__ adj, const float* __restrict__ h,
    const float* __restrict__ s1g, const float* __restrict__ s2g,
    const float* __restrict__ s2maxp, float* __restrict__ out) {
  __shared__ float p_lds[16][256];  // 16KB
  const int t = threadIdx.x;
  const int w = t >> 6;
  const int lane = t & 63;
  const int i0 = blockIdx.x * 16;
  const int jj0 = lane * 4;
  const float s2max = *s2maxp;
  float s1row[4], mrow[4], l_part[4], acc[4];
#pragma unroll
  for (int r = 0; r < 4; ++r) {
    s1row[r] = s1g[i0 + 4 * w + r];
    mrow[r] = lrelu(s1row[r] + s2max);  // static per-row upper bound on all scores
    l_part[r] = 0.f;
    acc[r] = 0.f;
  }
  for (int tile = 0; tile < NN / 256; ++tile) {
    const int j0 = tile * 256;
    // ---- Phase A: scores for my 4 rows, 4 j's per lane ----
    const float4 s2v = *(const float4*)(s2g + j0 + jj0);
#pragma unroll
    for (int r = 0; r < 4; ++r) {
      const int ii = 4 * w + r;
      const int4 av = *(const int4*)(adj + (size_t)(i0 + ii) * NN + j0 + jj0);
      const float s1v = s1row[r], mv = mrow[r];
      float p0 = av.x ? __expf(lrelu(s1v + s2v.x) - mv) : 0.f;
      float p1 = av.y ? __expf(lrelu(s1v + s2v.y) - mv) : 0.f;
      float p2 = av.z ? __expf(lrelu(s1v + s2v.z) - mv) : 0.f;
      float p3 = av.w ? __expf(lrelu(s1v + s2v.w) - mv) : 0.f;
      l_part[r] += (p0 + p1) + (p2 + p3);
      *(float4*)(&p_lds[ii][jj0]) = make_float4(p0, p1, p2, p3);
    }
    // no barrier: wave reads only its own rows (same-wave LDS ordering)
    // ---- Phase B: PV accumulate, lane = d ----
#pragma unroll 4
    for (int jj = 0; jj < 256; jj += 4) {
      const float* hp = h + (size_t)(j0 + jj) * FF + lane;
      float hv0 = hp[0];
      float hv1 = hp[FF];
      float hv2 = hp[2 * FF];
      float hv3 = hp[3 * FF];
#pragma unroll
      for (int r = 0; r < 4; ++r) {
        float4 pv = *(const float4*)(&p_lds[4 * w + r][jj]);
        float ar = acc[r];
        ar = fmaf(pv.x, hv0, ar);
        ar = fmaf(pv.y, hv1, ar);
        ar = fmaf(pv.z, hv2, ar);
        ar = fmaf(pv.w, hv3, ar);
        acc[r] = ar;
      }
    }
  }
  // epilogue: wave all-reduce of l, normalize, ELU
#pragma unroll
  for (int r = 0; r < 4; ++r) {
    float lv = l_part[r];
#pragma unroll
    for (int m = 32; m > 0; m >>= 1) lv += __shfl_xor(lv, m);
    float x = acc[r] / fmaxf(lv, 1e-30f);
    out[(size_t)(i0 + 4 * w + r) * FF + lane] = x > 0.f ? x : expm1f(x);
  }
}

extern "C" void kernel_launch(void* const* d_in, const int* in_sizes, int n_in,
                              void* d_out, int out_size, void* d_ws, size_t ws_size,
                              hipStream_t stream) {
  const float* feat = (const float*)d_in[0];
  const int* adj = (const int*)d_in[1];
  const float* W = (const float*)d_in[2];
  const float* a = (const float*)d_in[3];
  float* out = (float*)d_out;
  float* ws = (float*)d_ws;
  float* h = ws;                          // 8192*64
  float* s1 = h + (size_t)NN * FF;        // 8192
  float* s2 = s1 + NN;                    // 8192
  float* s2m = s2 + NN;                   // 1

  hipLaunchKernelGGL(k_h, dim3(NN / 16), dim3(256), 0, stream, feat, W, a, h, s1, s2);
  hipLaunchKernelGGL(k_s2max, dim3(1), dim3(256), 0, stream, s2, s2m);
  hipLaunchKernelGGL(k_attn, dim3(NN / 16), dim3(256), 0, stream, adj, h, s1, s2, s2m, out);
}

// Round 2
// 420.796 us; speedup vs baseline: 2.3307x; 2.3307x over previous
//
#include <hip/hip_runtime.h>
#include <hip/hip_bf16.h>
#include <math.h>

#define NN 8192
#define DD 256
#define FF 64
#define NSPLIT 8
#define JCHUNK (NN / NSPLIT)

typedef __attribute__((ext_vector_type(8))) short bf16x8;
typedef __attribute__((ext_vector_type(4))) float f32x4;

__device__ __forceinline__ float lrelu(float x) { return fmaxf(x, 0.2f * x); }
__device__ __forceinline__ short f2bf(float x) {
  union { __hip_bfloat16 b; short s; } u;
  u.b = __float2bfloat16(x);
  return u.s;
}

// ---------------------------------------------------------------------------
// Kernel 1: h = feat @ W via MFMA (bf16 inputs, f32 acc).
// Stores hT[d][i] (bf16) for the PV kernel, and s1/s2 from the f32 accs.
// Block = 256 thr = 4 waves, each wave 16 rows -> 64 rows/block, grid 128.
// A-frag: lane(m=i)=lane&15, k = (lane>>4)*8+idx  (feat, f32->bf16 on the fly)
// B-frag: lane(n=d)=lane&15, same k convention    (W^T staged bf16 in LDS,
//         XOR-swizzled to make the 16-row-strided ds_read_b128 conflict-free)
// ---------------------------------------------------------------------------
__global__ __launch_bounds__(256) void k_h(
    const float* __restrict__ feat, const float* __restrict__ W,
    const float* __restrict__ a, ushort* __restrict__ hT,
    float* __restrict__ s1, float* __restrict__ s2) {
  __shared__ __align__(16) ushort Wt[64 * 256];  // [d][k] bf16, swizzled
  const int t = threadIdx.x;
#pragma unroll
  for (int it = 0; it < 16; ++it) {
    int e4 = (it * 256 + t) * 4;  // element = k*64 + d
    int k = e4 >> 6;
    int d = e4 & 63;
    float4 wv = *(const float4*)(W + e4);
    Wt[((d + 0) * 256 + k) ^ (((d + 0) & 7) << 3)] = (ushort)f2bf(wv.x);
    Wt[((d + 1) * 256 + k) ^ (((d + 1) & 7) << 3)] = (ushort)f2bf(wv.y);
    Wt[((d + 2) * 256 + k) ^ (((d + 2) & 7) << 3)] = (ushort)f2bf(wv.z);
    Wt[((d + 3) * 256 + k) ^ (((d + 3) & 7) << 3)] = (ushort)f2bf(wv.w);
  }
  __syncthreads();
  const int lane = t & 63, w = t >> 6;
  const int il = lane & 15, kg = lane >> 4;
  const int ibase = blockIdx.x * 64 + w * 16;
  const float* frow = feat + (size_t)(ibase + il) * DD + kg * 8;
  f32x4 acc[4] = {{0,0,0,0},{0,0,0,0},{0,0,0,0},{0,0,0,0}};
  for (int k0 = 0; k0 < DD; k0 += 32) {
    float4 fa = *(const float4*)(frow + k0);
    float4 fb = *(const float4*)(frow + k0 + 4);
    bf16x8 av;
    av[0] = f2bf(fa.x); av[1] = f2bf(fa.y); av[2] = f2bf(fa.z); av[3] = f2bf(fa.w);
    av[4] = f2bf(fb.x); av[5] = f2bf(fb.y); av[6] = f2bf(fb.z); av[7] = f2bf(fb.w);
#pragma unroll
    for (int f = 0; f < 4; ++f) {
      int d = f * 16 + il;
      int idx = (d * 256 + k0 + kg * 8) ^ ((d & 7) << 3);
      bf16x8 bv = *(const bf16x8*)(&Wt[idx]);
      acc[f] = __builtin_amdgcn_mfma_f32_16x16x32_bf16(av, bv, acc[f], 0, 0, 0);
    }
  }
  // C/D layout: lane holds d = f*16 + il (col), i = ibase + kg*4 + reg (row)
  float a1v[4], a2v[4];
#pragma unroll
  for (int f = 0; f < 4; ++f) {
    a1v[f] = a[f * 16 + il];
    a2v[f] = a[FF + f * 16 + il];
  }
#pragma unroll
  for (int f = 0; f < 4; ++f) {
    int d = f * 16 + il;
    ushort4 hv;
    hv.x = (ushort)f2bf(acc[f][0]);
    hv.y = (ushort)f2bf(acc[f][1]);
    hv.z = (ushort)f2bf(acc[f][2]);
    hv.w = (ushort)f2bf(acc[f][3]);
    *(ushort4*)(hT + (size_t)d * NN + ibase + kg * 4) = hv;
  }
#pragma unroll
  for (int r = 0; r < 4; ++r) {
    float v1 = acc[0][r] * a1v[0] + acc[1][r] * a1v[1] +
               acc[2][r] * a1v[2] + acc[3][r] * a1v[3];
    float v2 = acc[0][r] * a2v[0] + acc[1][r] * a2v[1] +
               acc[2][r] * a2v[2] + acc[3][r] * a2v[3];
#pragma unroll
    for (int m = 1; m <= 8; m <<= 1) {
      v1 += __shfl_xor(v1, m);
      v2 += __shfl_xor(v2, m);
    }
    if (il == 0) {
      int i = ibase + kg * 4 + r;
      s1[i] = v1;
      s2[i] = v2;
    }
  }
}

// ---------------------------------------------------------------------------
// Kernel 2: fused mask+exp+PV via MFMA, j-split x NSPLIT for occupancy.
// Each wave: 16 rows, j-window JCHUNK, zero barriers.
// m_i = lrelu(s1_i + 8.0) is a static upper bound on all scores (s2max << 8),
// so the softmax is single-pass; the over-bound cancels in normalization.
// B-frag p[i][j]: lane computes i=il, j = jc*32 + kg*8 + idx (adj read int4,
// coalesced per 16-lane group). A-frag hT[d][j]: 16B global loads, L2-hot.
// Output Ot[d][i] frags: lane holds i = ibase+il, d = f*16 + kg*4 + reg;
// transposed via per-wave LDS tile into coalesced pacc[js][i][d] stores.
// ---------------------------------------------------------------------------
__global__ __launch_bounds__(256) void k_attn(
    const int* __restrict__ adj, const ushort* __restrict__ hT,
    const float* __restrict__ s1g, const float* __restrict__ s2g,
    float* __restrict__ pacc, float* __restrict__ pl) {
  __shared__ float tr[4][16][65];
  const int t = threadIdx.x;
  const int lane = t & 63, w = t >> 6;
  const int il = lane & 15, kg = lane >> 4;
  const int ig = blockIdx.x >> 3, js = blockIdx.x & 7;
  const int ibase = ig * 64 + w * 16;
  const int i = ibase + il;
  const float s1v = s1g[i];
  const float mi = lrelu(s1v + 8.0f);
  float lacc = 0.f;
  f32x4 acc[4] = {{0,0,0,0},{0,0,0,0},{0,0,0,0},{0,0,0,0}};
  const size_t arow = (size_t)i * NN;
  const int jbase = js * JCHUNK + kg * 8;
#pragma unroll 2
  for (int jc = 0; jc < JCHUNK / 32; ++jc) {
    const int jl = jbase + jc * 32;
    const int4 av0 = *(const int4*)(adj + arow + jl);
    const int4 av1 = *(const int4*)(adj + arow + jl + 4);
    const float4 sa = *(const float4*)(s2g + jl);
    const float4 sb = *(const float4*)(s2g + jl + 4);
    float p0 = av0.x ? __expf(lrelu(s1v + sa.x) - mi) : 0.f;
    float p1 = av0.y ? __expf(lrelu(s1v + sa.y) - mi) : 0.f;
    float p2 = av0.z ? __expf(lrelu(s1v + sa.z) - mi) : 0.f;
    float p3 = av0.w ? __expf(lrelu(s1v + sa.w) - mi) : 0.f;
    float p4 = av1.x ? __expf(lrelu(s1v + sb.x) - mi) : 0.f;
    float p5 = av1.y ? __expf(lrelu(s1v + sb.y) - mi) : 0.f;
    float p6 = av1.z ? __expf(lrelu(s1v + sb.z) - mi) : 0.f;
    float p7 = av1.w ? __expf(lrelu(s1v + sb.w) - mi) : 0.f;
    lacc += ((p0 + p1) + (p2 + p3)) + ((p4 + p5) + (p6 + p7));
    bf16x8 pb;
    pb[0] = f2bf(p0); pb[1] = f2bf(p1); pb[2] = f2bf(p2); pb[3] = f2bf(p3);
    pb[4] = f2bf(p4); pb[5] = f2bf(p5); pb[6] = f2bf(p6); pb[7] = f2bf(p7);
#pragma unroll
    for (int f = 0; f < 4; ++f) {
      const bf16x8 hv = *(const bf16x8*)(hT + (size_t)(f * 16 + il) * NN + jl);
      acc[f] = __builtin_amdgcn_mfma_f32_16x16x32_bf16(hv, pb, acc[f], 0, 0, 0);
    }
  }
  lacc += __shfl_xor(lacc, 16);
  lacc += __shfl_xor(lacc, 32);
  if (lane < 16) pl[(size_t)js * NN + ibase + lane] = lacc;
  // transpose: lane holds i = ibase+il, d = f*16 + kg*4 + r
#pragma unroll
  for (int f = 0; f < 4; ++f)
#pragma unroll
    for (int r = 0; r < 4; ++r) tr[w][il][f * 16 + kg * 4 + r] = acc[f][r];
  // same-wave write->read: no barrier needed
#pragma unroll
  for (int r = 0; r < 16; ++r)
    pacc[((size_t)js * NN + ibase + r) * FF + lane] = tr[w][r][lane];
}

// ---------------------------------------------------------------------------
// Kernel 3: combine partials, normalize, ELU. Fully coalesced.
// ---------------------------------------------------------------------------
__global__ __launch_bounds__(256) void k_combine(
    const float* __restrict__ pacc, const float* __restrict__ pl,
    float* __restrict__ out) {
  const int idx = blockIdx.x * 256 + threadIdx.x;
  const int i = idx >> 6;
  float s = 0.f, L = 0.f;
#pragma unroll
  for (int sp = 0; sp < NSPLIT; ++sp) {
    s += pacc[(size_t)sp * NN * FF + idx];
    L += pl[(size_t)sp * NN + i];
  }
  float x = s / fmaxf(L, 1e-30f);
  out[idx] = x > 0.f ? x : expm1f(x);
}

extern "C" void kernel_launch(void* const* d_in, const int* in_sizes, int n_in,
                              void* d_out, int out_size, void* d_ws, size_t ws_size,
                              hipStream_t stream) {
  const float* feat = (const float*)d_in[0];
  const int* adj = (const int*)d_in[1];
  const float* W = (const float*)d_in[2];
  const float* a = (const float*)d_in[3];
  float* out = (float*)d_out;

  ushort* hT = (ushort*)d_ws;                       // 64*8192 bf16 = 1 MB
  float* s1 = (float*)(hT + (size_t)FF * NN);       // 8192 f32
  float* s2 = s1 + NN;                              // 8192 f32
  float* pl = s2 + NN;                              // NSPLIT*8192 f32
  float* pacc = pl + (size_t)NSPLIT * NN;           // NSPLIT*8192*64 f32 (16 MB)

  hipLaunchKernelGGL(k_h, dim3(NN / 64), dim3(256), 0, stream, feat, W, a, hT, s1, s2);
  hipLaunchKernelGGL(k_attn, dim3((NN / 64) * NSPLIT), dim3(256), 0, stream,
                     adj, hT, s1, s2, pacc, pl);
  hipLaunchKernelGGL(k_combine, dim3(NN * FF / 256), dim3(256), 0, stream,
                     pacc, pl, out);
}

// Round 3
// 417.318 us; speedup vs baseline: 2.3501x; 1.0083x over previous
//
#include <hip/hip_runtime.h>
#include <hip/hip_bf16.h>
#include <math.h>

#define NN 8192
#define DD 256
#define FF 64
#define NSPLIT 16
#define JCHUNK (NN / NSPLIT)

typedef __attribute__((ext_vector_type(8))) short bf16x8;
typedef __attribute__((ext_vector_type(4))) float f32x4;

__device__ __forceinline__ float lrelu(float x) { return fmaxf(x, 0.2f * x); }
__device__ __forceinline__ short f2bf(float x) {
  union { __hip_bfloat16 b; short s; } u;
  u.b = __float2bfloat16(x);
  return u.s;
}

// ---------------------------------------------------------------------------
// k_pre: W [256][64] f32 -> WT [64][256] bf16 (one-time, L2-resident after).
// ---------------------------------------------------------------------------
__global__ __launch_bounds__(256) void k_pre(const float* __restrict__ W,
                                             ushort* __restrict__ WT) {
  const int e4 = (blockIdx.x * 256 + threadIdx.x) * 4;  // element = k*64 + d
  const float4 wv = *(const float4*)(W + e4);
  const int k = e4 >> 6, d = e4 & 63;
  WT[(d + 0) * DD + k] = (ushort)f2bf(wv.x);
  WT[(d + 1) * DD + k] = (ushort)f2bf(wv.y);
  WT[(d + 2) * DD + k] = (ushort)f2bf(wv.z);
  WT[(d + 3) * DD + k] = (ushort)f2bf(wv.w);
}

// ---------------------------------------------------------------------------
// k_h: h = feat @ W via MFMA, f-split for occupancy.
// Block = 16 rows, 4 waves; wave w computes d-slab [w*16, w*16+16).
// Each wave: 1 mfma_16x16x32 per 32-k chunk (A = feat rows bf16-on-the-fly,
// B = WT slab, 16B global loads, L2-hot). 512 blocks -> 2048 waves (8/CU).
// Outputs: hT[d][i] bf16, s1/s2 from f32 accs (cross-wave LDS reduce).
// Layout convention (HW-verified rounds 1-2): lane&15 <-> B index (d),
// (lane>>4)*4+reg <-> A index (i).
// ---------------------------------------------------------------------------
__global__ __launch_bounds__(256) void k_h(
    const float* __restrict__ feat, const ushort* __restrict__ WT,
    const float* __restrict__ a, ushort* __restrict__ hT,
    float* __restrict__ s1, float* __restrict__ s2) {
  __shared__ float sp1[4][16], sp2[4][16];
  const int t = threadIdx.x, lane = t & 63, w = t >> 6;
  const int il = lane & 15, kg = lane >> 4;
  const int ibase = blockIdx.x * 16;
  const int d = w * 16 + il;
  const float* frow = feat + (size_t)(ibase + il) * DD + kg * 8;
  const ushort* wrow = WT + (size_t)d * DD + kg * 8;
  f32x4 acc = {0.f, 0.f, 0.f, 0.f};
#pragma unroll
  for (int k0 = 0; k0 < DD; k0 += 32) {
    const float4 fa = *(const float4*)(frow + k0);
    const float4 fb = *(const float4*)(frow + k0 + 4);
    bf16x8 av;
    av[0] = f2bf(fa.x); av[1] = f2bf(fa.y); av[2] = f2bf(fa.z); av[3] = f2bf(fa.w);
    av[4] = f2bf(fb.x); av[5] = f2bf(fb.y); av[6] = f2bf(fb.z); av[7] = f2bf(fb.w);
    const bf16x8 bv = *(const bf16x8*)(wrow + k0);
    acc = __builtin_amdgcn_mfma_f32_16x16x32_bf16(av, bv, acc, 0, 0, 0);
  }
  // lane holds i = ibase + kg*4 + r (r=0..3) for column d
  ushort4 hv;
  hv.x = (ushort)f2bf(acc[0]);
  hv.y = (ushort)f2bf(acc[1]);
  hv.z = (ushort)f2bf(acc[2]);
  hv.w = (ushort)f2bf(acc[3]);
  *(ushort4*)(hT + (size_t)d * NN + ibase + kg * 4) = hv;
  // s1/s2: per-d contribution, reduce over il (16 d's of this wave), then waves
  const float a1v = a[d], a2v = a[FF + d];
#pragma unroll
  for (int r = 0; r < 4; ++r) {
    float v1 = acc[r] * a1v;
    float v2 = acc[r] * a2v;
#pragma unroll
    for (int m = 1; m <= 8; m <<= 1) {
      v1 += __shfl_xor(v1, m);
      v2 += __shfl_xor(v2, m);
    }
    if (il == 0) {
      sp1[w][kg * 4 + r] = v1;
      sp2[w][kg * 4 + r] = v2;
    }
  }
  __syncthreads();
  if (t < 16) {
    s1[ibase + t] = sp1[0][t] + sp1[1][t] + sp1[2][t] + sp1[3][t];
    s2[ibase + t] = sp2[0][t] + sp2[1][t] + sp2[2][t] + sp2[3][t];
  }
}

// ---------------------------------------------------------------------------
// k_attn: fused mask+exp+PV via MFMA, j-split x16 (grid 2048, 32 waves/CU).
// Each wave: 16 rows, j-window 512, zero barriers.
// m_i = lrelu(s1_i + 8.0) static upper bound (|s2max| << 8); single-pass
// softmax, over-bound cancels in normalization.
// ---------------------------------------------------------------------------
__global__ __launch_bounds__(256) void k_attn(
    const int* __restrict__ adj, const ushort* __restrict__ hT,
    const float* __restrict__ s1g, const float* __restrict__ s2g,
    float* __restrict__ pacc, float* __restrict__ pl) {
  __shared__ float tr[4][16][65];
  const int t = threadIdx.x;
  const int lane = t & 63, w = t >> 6;
  const int il = lane & 15, kg = lane >> 4;
  const int ig = blockIdx.x >> 4, js = blockIdx.x & 15;
  const int ibase = ig * 64 + w * 16;
  const int i = ibase + il;
  const float s1v = s1g[i];
  const float mi = lrelu(s1v + 8.0f);
  float lacc = 0.f;
  f32x4 acc[4] = {{0,0,0,0},{0,0,0,0},{0,0,0,0},{0,0,0,0}};
  const size_t arow = (size_t)i * NN;
  const int jbase = js * JCHUNK + kg * 8;
#pragma unroll 4
  for (int jc = 0; jc < JCHUNK / 32; ++jc) {
    const int jl = jbase + jc * 32;
    const int4 av0 = *(const int4*)(adj + arow + jl);
    const int4 av1 = *(const int4*)(adj + arow + jl + 4);
    const float4 sa = *(const float4*)(s2g + jl);
    const float4 sb = *(const float4*)(s2g + jl + 4);
    float p0 = av0.x ? __expf(lrelu(s1v + sa.x) - mi) : 0.f;
    float p1 = av0.y ? __expf(lrelu(s1v + sa.y) - mi) : 0.f;
    float p2 = av0.z ? __expf(lrelu(s1v + sa.z) - mi) : 0.f;
    float p3 = av0.w ? __expf(lrelu(s1v + sa.w) - mi) : 0.f;
    float p4 = av1.x ? __expf(lrelu(s1v + sb.x) - mi) : 0.f;
    float p5 = av1.y ? __expf(lrelu(s1v + sb.y) - mi) : 0.f;
    float p6 = av1.z ? __expf(lrelu(s1v + sb.z) - mi) : 0.f;
    float p7 = av1.w ? __expf(lrelu(s1v + sb.w) - mi) : 0.f;
    lacc += ((p0 + p1) + (p2 + p3)) + ((p4 + p5) + (p6 + p7));
    bf16x8 pb;
    pb[0] = f2bf(p0); pb[1] = f2bf(p1); pb[2] = f2bf(p2); pb[3] = f2bf(p3);
    pb[4] = f2bf(p4); pb[5] = f2bf(p5); pb[6] = f2bf(p6); pb[7] = f2bf(p7);
#pragma unroll
    for (int f = 0; f < 4; ++f) {
      const bf16x8 hv = *(const bf16x8*)(hT + (size_t)(f * 16 + il) * NN + jl);
      acc[f] = __builtin_amdgcn_mfma_f32_16x16x32_bf16(hv, pb, acc[f], 0, 0, 0);
    }
  }
  lacc += __shfl_xor(lacc, 16);
  lacc += __shfl_xor(lacc, 32);
  if (lane < 16) pl[(size_t)js * NN + ibase + lane] = lacc;
  // transpose: lane holds i = ibase+il, d = f*16 + kg*4 + r
#pragma unroll
  for (int f = 0; f < 4; ++f)
#pragma unroll
    for (int r = 0; r < 4; ++r) tr[w][il][f * 16 + kg * 4 + r] = acc[f][r];
  // same-wave write->read: no barrier needed
#pragma unroll
  for (int r = 0; r < 16; ++r)
    pacc[((size_t)js * NN + ibase + r) * FF + lane] = tr[w][r][lane];
}

// ---------------------------------------------------------------------------
// k_combine: sum partials, normalize, ELU. Fully coalesced.
// ---------------------------------------------------------------------------
__global__ __launch_bounds__(256) void k_combine(
    const float* __restrict__ pacc, const float* __restrict__ pl,
    float* __restrict__ out) {
  const int idx = blockIdx.x * 256 + threadIdx.x;
  const int i = idx >> 6;
  float s = 0.f, L = 0.f;
#pragma unroll
  for (int sp = 0; sp < NSPLIT; ++sp) {
    s += pacc[(size_t)sp * NN * FF + idx];
    L += pl[(size_t)sp * NN + i];
  }
  float x = s / fmaxf(L, 1e-30f);
  out[idx] = x > 0.f ? x : expm1f(x);
}

extern "C" void kernel_launch(void* const* d_in, const int* in_sizes, int n_in,
                              void* d_out, int out_size, void* d_ws, size_t ws_size,
                              hipStream_t stream) {
  const float* feat = (const float*)d_in[0];
  const int* adj = (const int*)d_in[1];
  const float* W = (const float*)d_in[2];
  const float* a = (const float*)d_in[3];
  float* out = (float*)d_out;

  ushort* hT = (ushort*)d_ws;                       // 64*8192 bf16 = 1 MB
  ushort* WT = hT + (size_t)FF * NN;                // 64*256 bf16 = 32 KB
  float* s1 = (float*)(WT + (size_t)FF * DD);       // 8192 f32
  float* s2 = s1 + NN;                              // 8192 f32
  float* pl = s2 + NN;                              // NSPLIT*8192 f32
  float* pacc = pl + (size_t)NSPLIT * NN;           // NSPLIT*8192*64 f32 (33.5 MB)

  hipLaunchKernelGGL(k_pre, dim3(DD * FF / 1024), dim3(256), 0, stream, W, WT);
  hipLaunchKernelGGL(k_h, dim3(NN / 16), dim3(256), 0, stream, feat, WT, a, hT, s1, s2);
  hipLaunchKernelGGL(k_attn, dim3((NN / 64) * NSPLIT), dim3(256), 0, stream,
                     adj, hT, s1, s2, pacc, pl);
  hipLaunchKernelGGL(k_combine, dim3(NN * FF / 256), dim3(256), 0, stream,
                     pacc, pl, out);
}

// Round 4
// 386.868 us; speedup vs baseline: 2.5351x; 1.0787x over previous
//
#include <hip/hip_runtime.h>
#include <hip/hip_bf16.h>
#include <math.h>

#define NN 8192
#define DD 256
#define FF 64
#define NSPLIT 16
#define JCHUNK (NN / NSPLIT)  // 512
#define CT 128                // j columns staged per round
#define NT (JCHUNK / CT)      // 4

typedef __attribute__((ext_vector_type(8))) short bf16x8;
typedef __attribute__((ext_vector_type(4))) float f32x4;

__device__ __forceinline__ float lrelu(float x) { return fmaxf(x, 0.2f * x); }
__device__ __forceinline__ ushort f2bf(float x) {
  union { __hip_bfloat16 b; ushort s; } u;
  u.b = __float2bfloat16(x);
  return u.s;
}
__device__ __forceinline__ float bf2f(ushort s) {
  union { uint u; float f; } v;
  v.u = (uint)s << 16;
  return v.f;
}

// ---------------------------------------------------------------------------
// k_pre: W [256][64] f32 -> WT [64][256] bf16.
// ---------------------------------------------------------------------------
__global__ __launch_bounds__(256) void k_pre(const float* __restrict__ W,
                                             ushort* __restrict__ WT) {
  const int e4 = (blockIdx.x * 256 + threadIdx.x) * 4;  // element = k*64 + d
  const float4 wv = *(const float4*)(W + e4);
  const int k = e4 >> 6, d = e4 & 63;
  WT[(d + 0) * DD + k] = f2bf(wv.x);
  WT[(d + 1) * DD + k] = f2bf(wv.y);
  WT[(d + 2) * DD + k] = f2bf(wv.z);
  WT[(d + 3) * DD + k] = f2bf(wv.w);
}

// ---------------------------------------------------------------------------
// k_h: h = feat @ W via MFMA (structure verified round 3; only the h store
// target changed). Wave w = f-slab [w*16, w*16+16). Output in FRAGMENT ORDER:
// hTf ushort index ((f*256 + j32)*64 + (kg*16+il))*8 + e  represents
// hT[d = f*16+il][j = j32*32 + kg*8 + e]  -> PV loads become lane-coalesced.
// Also s1 = h@a1, s2 = h@a2 from the f32 accumulators.
// ---------------------------------------------------------------------------
__global__ __launch_bounds__(256) void k_h(
    const float* __restrict__ feat, const ushort* __restrict__ WT,
    const float* __restrict__ a, ushort* __restrict__ hTf,
    float* __restrict__ s1, float* __restrict__ s2) {
  __shared__ float sp1[4][16], sp2[4][16];
  const int t = threadIdx.x, lane = t & 63, w = t >> 6;
  const int il = lane & 15, kg = lane >> 4;
  const int ibase = blockIdx.x * 16;
  const int d = w * 16 + il;
  const float* frow = feat + (size_t)(ibase + il) * DD + kg * 8;
  const ushort* wrow = WT + (size_t)d * DD + kg * 8;
  f32x4 acc = {0.f, 0.f, 0.f, 0.f};
#pragma unroll
  for (int k0 = 0; k0 < DD; k0 += 32) {
    const float4 fa = *(const float4*)(frow + k0);
    const float4 fb = *(const float4*)(frow + k0 + 4);
    bf16x8 av;
    av[0] = f2bf(fa.x); av[1] = f2bf(fa.y); av[2] = f2bf(fa.z); av[3] = f2bf(fa.w);
    av[4] = f2bf(fb.x); av[5] = f2bf(fb.y); av[6] = f2bf(fb.z); av[7] = f2bf(fb.w);
    const bf16x8 bv = *(const bf16x8*)(wrow + k0);
    acc = __builtin_amdgcn_mfma_f32_16x16x32_bf16(av, bv, acc, 0, 0, 0);
  }
  // lane holds i = ibase + kg*4 + r for column d; store to fragment order
  ushort4 hv;
  hv.x = f2bf(acc[0]);
  hv.y = f2bf(acc[1]);
  hv.z = f2bf(acc[2]);
  hv.w = f2bf(acc[3]);
  {
    const int i0q = ibase + kg * 4;                 // 4-aligned
    const size_t hb = ((size_t)(w * 256 + (i0q >> 5)) * 64 +
                       ((i0q >> 3) & 3) * 16 + il) * 8 + (i0q & 7);
    *(ushort4*)(hTf + hb) = hv;
  }
  const float a1v = a[d], a2v = a[FF + d];
#pragma unroll
  for (int r = 0; r < 4; ++r) {
    float v1 = acc[r] * a1v;
    float v2 = acc[r] * a2v;
#pragma unroll
    for (int m = 1; m <= 8; m <<= 1) {
      v1 += __shfl_xor(v1, m);
      v2 += __shfl_xor(v2, m);
    }
    if (il == 0) {
      sp1[w][kg * 4 + r] = v1;
      sp2[w][kg * 4 + r] = v2;
    }
  }
  __syncthreads();
  if (t < 16) {
    s1[ibase + t] = sp1[0][t] + sp1[1][t] + sp1[2][t] + sp1[3][t];
    s2[ibase + t] = sp2[0][t] + sp2[1][t] + sp2[2][t] + sp2[3][t];
  }
}

// ---------------------------------------------------------------------------
// k_attn: fused mask+exp+PV. Grid 2048 = 128 i-groups x 16 j-splits.
// Per wave: 16 rows, 512-j window, NO barriers (wave-private LDS tiles).
// Phase A: adj read COALESCED (each instr: 2 rows x 512B contiguous),
//   p = adj ? exp(lrelu(s1+s2)-mi) : 0 computed lane<->j, packed bf16,
//   written to XOR-swizzled wave LDS tile (byte ^= (row&7)<<4).
// Phase B: ds_read_b128 B-fragments (swizzle-matched), hTf A-fragments
//   coalesced 16B/lane, 4 MFMA per 32-j; l summed from the SAME bf16 p.
// m_i = lrelu(s1_i + 8) static upper bound; single-pass softmax.
// ---------------------------------------------------------------------------
__global__ __launch_bounds__(256) void k_attn(
    const int* __restrict__ adj, const ushort* __restrict__ hTf,
    const float* __restrict__ s1g, const float* __restrict__ s2g,
    float* __restrict__ pacc, float* __restrict__ pl) {
  __shared__ __align__(16) char smem[4][4480];  // per-wave: p-tile 4KB / tr 4.2KB
  __shared__ float s1w[4][16];
  const int t = threadIdx.x;
  const int lane = t & 63, w = t >> 6;
  const int il = lane & 15, kg = lane >> 4;
  const int ig = blockIdx.x >> 4, js = blockIdx.x & 15;
  const int rbase = ig * 64 + w * 16;  // this wave's first row
  const int jwin0 = js * JCHUNK;
  char* const smemw = smem[w];

  if (lane < 16) s1w[w][lane] = s1g[rbase + lane];  // same-wave LDS, no barrier
  const int arow = lane >> 5;          // 0/1: which of 2 rows this lane loads
  const int acol = (lane & 31) * 4;    // 4 consecutive j per lane
  const int* ap = adj + (size_t)(rbase + arow) * NN + jwin0 + acol;

  float lacc = 0.f;
  f32x4 acc[4] = {{0,0,0,0},{0,0,0,0},{0,0,0,0},{0,0,0,0}};

  for (int tile = 0; tile < NT; ++tile) {
    const int jt = jwin0 + tile * CT;
    // ---- Phase A ----
    const float4 s2v = *(const float4*)(s2g + jt + acol);
#pragma unroll
    for (int rep = 0; rep < 8; ++rep) {
      const int r = rep * 2 + arow;
      const int4 av = *(const int4*)(ap + (size_t)rep * 2 * NN + tile * CT);
      const float s1v = s1w[w][r];
      const float mi = lrelu(s1v + 8.0f);
      ushort4 pk;
      pk.x = av.x ? f2bf(__expf(lrelu(s1v + s2v.x) - mi)) : (ushort)0;
      pk.y = av.y ? f2bf(__expf(lrelu(s1v + s2v.y) - mi)) : (ushort)0;
      pk.z = av.z ? f2bf(__expf(lrelu(s1v + s2v.z) - mi)) : (ushort)0;
      pk.w = av.w ? f2bf(__expf(lrelu(s1v + s2v.w) - mi)) : (ushort)0;
      const int swz = r * 256 + ((acol * 2) ^ ((r & 7) << 4));
      *(ushort4*)(smemw + swz) = pk;
    }
    // ---- Phase B (same-wave LDS write->read; compiler orders via lgkmcnt) ----
#pragma unroll
    for (int sb = 0; sb < 4; ++sb) {
      const int coff = (sb * 32 + kg * 8) * 2;
      const bf16x8 pb = *(const bf16x8*)(smemw + il * 256 + (coff ^ ((il & 7) << 4)));
      float ps = 0.f;
#pragma unroll
      for (int e = 0; e < 8; ++e) ps += bf2f((ushort)pb[e]);
      lacc += ps;
      const int j32 = (jt >> 5) + sb;
#pragma unroll
      for (int f = 0; f < 4; ++f) {
        const bf16x8 hv =
            *(const bf16x8*)(hTf + ((size_t)(f * 256 + j32) * 64 + lane) * 8);
        acc[f] = __builtin_amdgcn_mfma_f32_16x16x32_bf16(hv, pb, acc[f], 0, 0, 0);
      }
    }
  }
  // l: lane (il,kg) holds row il's partial over its kg j-subset
  lacc += __shfl_xor(lacc, 16);
  lacc += __shfl_xor(lacc, 32);
  if (lane < 16) pl[(size_t)js * NN + rbase + lane] = lacc;
  // C/D: lane holds i = rbase + il (col), d = f*16 + kg*4 + r (row)
  float (*tr)[65] = (float(*)[65])smemw;
#pragma unroll
  for (int f = 0; f < 4; ++f)
#pragma unroll
    for (int r = 0; r < 4; ++r) tr[il][f * 16 + kg * 4 + r] = acc[f][r];
#pragma unroll
  for (int r = 0; r < 16; ++r)
    pacc[((size_t)js * NN + rbase + r) * FF + lane] = tr[r][lane];
}

// ---------------------------------------------------------------------------
// k_combine: sum partials, normalize, ELU. Fully coalesced.
// ---------------------------------------------------------------------------
__global__ __launch_bounds__(256) void k_combine(
    const float* __restrict__ pacc, const float* __restrict__ pl,
    float* __restrict__ out) {
  const int idx = blockIdx.x * 256 + threadIdx.x;
  const int i = idx >> 6;
  float s = 0.f, L = 0.f;
#pragma unroll
  for (int sp = 0; sp < NSPLIT; ++sp) {
    s += pacc[(size_t)sp * NN * FF + idx];
    L += pl[(size_t)sp * NN + i];
  }
  float x = s / fmaxf(L, 1e-30f);
  out[idx] = x > 0.f ? x : expm1f(x);
}

extern "C" void kernel_launch(void* const* d_in, const int* in_sizes, int n_in,
                              void* d_out, int out_size, void* d_ws, size_t ws_size,
                              hipStream_t stream) {
  const float* feat = (const float*)d_in[0];
  const int* adj = (const int*)d_in[1];
  const float* W = (const float*)d_in[2];
  const float* a = (const float*)d_in[3];
  float* out = (float*)d_out;

  ushort* hTf = (ushort*)d_ws;                      // 4*256*64*8 bf16 = 1 MB
  ushort* WT = hTf + (size_t)FF * NN;               // 64*256 bf16 = 32 KB
  float* s1 = (float*)(WT + (size_t)FF * DD);       // 8192 f32
  float* s2 = s1 + NN;                              // 8192 f32
  float* pl = s2 + NN;                              // NSPLIT*8192 f32
  float* pacc = pl + (size_t)NSPLIT * NN;           // NSPLIT*8192*64 f32 (33.5 MB)

  hipLaunchKernelGGL(k_pre, dim3(DD * FF / 1024), dim3(256), 0, stream, W, WT);
  hipLaunchKernelGGL(k_h, dim3(NN / 16), dim3(256), 0, stream, feat, WT, a, hTf, s1, s2);
  hipLaunchKernelGGL(k_attn, dim3((NN / 64) * NSPLIT), dim3(256), 0, stream,
                     adj, hTf, s1, s2, pacc, pl);
  hipLaunchKernelGGL(k_combine, dim3(NN * FF / 256), dim3(256), 0, stream,
                     pacc, pl, out);
}